// Round 4
// baseline (369.837 us; speedup 1.0000x reference)
//
#include <hip/hip_runtime.h>
#include <cstdint>
#include <cstddef>

#define N_PTS   16384
#define K_CODES 8192
#define DIM     256
#define DECAYF  0.99f
#define OMDF    0.01f
#define EPSF    1e-5f

// output layout (float32, concatenated in reference return order)
#define OFF_ZQ   0
#define OFF_LOSS 4194304
#define OFF_IDX  4194305
#define OFF_W    4210689
#define OFF_CS   6307841
#define OFF_EA   6316033

// scratch parked inside output regions that are written later:
//  zb  = bf16[16384*256] at out+OFF_ZQ            (8 MB, = 128*z)  } z_q region,
//  wb  = bf16[ 8192*256] at out+OFF_ZQ+2097152    (4 MB)           } dead after
//  hen = f32 [ 8192]     at out+OFF_ZQ+3145728    (32 KB)          } k_gemm
//  c1,c2 = u32[64][16384] x2 at out+OFF_W         (8 MB exact fit; dead after
//                                                  k_rescore; k_gather rewrites)
#define ZB_OFF   OFF_ZQ
#define WB_OFF   (OFF_ZQ + 2097152)
#define HEN_OFF  (OFF_ZQ + 3145728)
#define C1_OFF   OFF_W
#define C2_OFF   (OFF_W + 1048576)

typedef __attribute__((ext_vector_type(8))) short bf16x8;
typedef __attribute__((ext_vector_type(4))) float f32x4;

__device__ inline unsigned short f2b(float f) {  // fp32 -> bf16 bits, RNE
    unsigned u = __float_as_uint(f);
    return (unsigned short)((u + 0x7FFFu + ((u >> 16) & 1u)) >> 16);
}

__device__ inline unsigned umaxu(unsigned a, unsigned b) { return a > b ? a : b; }
__device__ inline unsigned uminu(unsigned a, unsigned b) { return a < b ? a : b; }

__device__ inline void gload16(const void* g, void* l) {
    __builtin_amdgcn_global_load_lds(
        (const __attribute__((address_space(1))) unsigned int*)g,
        (__attribute__((address_space(3))) unsigned int*)l, 16, 0, 0);
}

// ---- 1. fp32 -> bf16 (z scaled by 128) + per-point ||z||^2 + hen + cnt zero -
__global__ void k_cvt2(const float* __restrict__ z, short* __restrict__ zb,
                       const float* __restrict__ w, short* __restrict__ wb,
                       float* __restrict__ hen, unsigned* __restrict__ cnt,
                       float* __restrict__ zn2) {
    const int tid = threadIdx.x;
    if (blockIdx.x < N_PTS * DIM / 2048) {
        size_t base = (size_t)(blockIdx.x * 256 + tid) * 8;
        float4 a = *(const float4*)(z + base);
        float4 b = *(const float4*)(z + base + 4);
        bf16x8 o;                                   // zb = 128*z (exact scale)
        o[0] = (short)f2b(128.f * a.x); o[1] = (short)f2b(128.f * a.y);
        o[2] = (short)f2b(128.f * a.z); o[3] = (short)f2b(128.f * a.w);
        o[4] = (short)f2b(128.f * b.x); o[5] = (short)f2b(128.f * b.y);
        o[6] = (short)f2b(128.f * b.z); o[7] = (short)f2b(128.f * b.w);
        *(bf16x8*)(zb + base) = o;
        // per-point ||z||^2 (32 threads per point)
        float s = a.x * a.x + a.y * a.y + a.z * a.z + a.w * a.w
                + b.x * b.x + b.y * b.y + b.z * b.z + b.w * b.w;
        #pragma unroll
        for (int m = 16; m >= 1; m >>= 1) s += __shfl_xor(s, m, 64);
        if ((tid & 31) == 0) zn2[blockIdx.x * 8 + (tid >> 5)] = s;
    } else {
        int blk = blockIdx.x - N_PTS * DIM / 2048;
        size_t base = (size_t)(blk * 256 + tid) * 8;
        float4 a = *(const float4*)(w + base);
        float4 b = *(const float4*)(w + base + 4);
        bf16x8 o;
        o[0] = (short)f2b(a.x); o[1] = (short)f2b(a.y);
        o[2] = (short)f2b(a.z); o[3] = (short)f2b(a.w);
        o[4] = (short)f2b(b.x); o[5] = (short)f2b(b.y);
        o[6] = (short)f2b(b.z); o[7] = (short)f2b(b.w);
        *(bf16x8*)(wb + base) = o;
        float s = a.x * a.x + a.y * a.y + a.z * a.z + a.w * a.w
                + b.x * b.x + b.y * b.y + b.z * b.z + b.w * b.w;
        #pragma unroll
        for (int m = 16; m >= 1; m >>= 1) s += __shfl_xor(s, m, 64);
        if ((tid & 31) == 0) hen[base >> 8] = 0.5f * s;
        int gid = blk * 256 + tid;
        if (gid < K_CODES) cnt[gid] = 0u;
    }
}

// ---- 2. bf16 MFMA GEMM, 128x128 tile, 4 waves (2Mx2N), 5 blocks/CU ----------
// Evidence R0-R3: MfmaUtil ~ 1.9% x waves/CU across all structures -> this
// kernel family is latency/TLP-bound. So: round-0's proven 2-phase structure
// (stage -> sync -> compute; 0 bank conflicts measured) with two changes only:
//  (1) __launch_bounds__(256,5): LDS 32 KB x 5 = 160 KB exact, regs 124
//      (60 VGPR + 64 AGPR) -> 5 blocks/CU = 20 waves/CU (was 16).
//  (2) wave tile 32x128 -> 64x64 (acc[4][4]): LDS-read B/FLOP 0.039 -> 0.031
//      (-20% port pressure, the projected next wall), b-frags 8 -> 4.
// Staging, swizzle, de-swizzle (row&7 == lane&7 holds: all row offsets are
// multiples of 8), key packing, accumulation order (dc 0..3 x kk 0..1) are
// verbatim round 0; 64-code top-2 + wn-pair LDS merge verbatim round 3.
// c1/c2 layout [64][16384] unchanged -> downstream untouched.
__global__ __launch_bounds__(256, 5) void k_gemm(const short* __restrict__ zb,
                                                 const short* __restrict__ wb,
                                                 const float* __restrict__ hen,
                                                 unsigned* __restrict__ c1,
                                                 unsigned* __restrict__ c2) {
    __shared__ __align__(16) short As[128 * 64];   // 16 KB
    __shared__ __align__(16) short Bs[128 * 64];   // 16 KB

    const int tid  = threadIdx.x;
    const int lane = tid & 63;
    const int wv   = tid >> 6;               // 0..3
    const int wm   = wv >> 1;                // 0..1  (z half: 64 rows)
    const int wn   = wv & 1;                 // 0..1  (code half: 64 cols)
    const int ztile = blockIdx.x & 127;      // kt-major: 128 blocks share B-tile
    const int kt    = blockIdx.x >> 7;       // 0..63
    const int z0 = ztile * 128, k0g = kt * 128;
    const int col = lane & 15;
    const int hi  = lane >> 4;
    const int x7  = lane & 7;

    f32x4 acc[4][4];
    #pragma unroll
    for (int ni = 0; ni < 4; ni++) {
        float h = 131072.0f - 128.0f * hen[k0g + wn * 64 + ni * 16 + col];
        f32x4 iv = {h, h, h, h};
        #pragma unroll
        for (int mi = 0; mi < 4; mi++) acc[mi][ni] = iv;
    }
    const unsigned invL = (unsigned)(K_CODES - 1 - (k0g + wn * 64 + col));

    const int srow = lane >> 3;                       // 0..7 within segment
    const int scol = ((lane & 7) ^ srow) * 8;         // swizzled source chunk

    #pragma unroll 1
    for (int dc = 0; dc < 4; ++dc) {
        __syncthreads();
        #pragma unroll
        for (int s4 = 0; s4 < 4; ++s4) {
            int seg = wv * 4 + s4;                    // 16 segments of 8 rows
            gload16(zb + (size_t)(z0 + seg * 8 + srow) * DIM + dc * 64 + scol,
                    As + seg * 512 + lane * 8);
            gload16(wb + (size_t)(k0g + seg * 8 + srow) * DIM + dc * 64 + scol,
                    Bs + seg * 512 + lane * 8);
        }
        __syncthreads();
        #pragma unroll
        for (int kk = 0; kk < 2; ++kk) {
            const int ch8 = ((((kk << 2) + hi) ^ x7) << 3);   // de-swizzle
            bf16x8 b[4];
            #pragma unroll
            for (int ni = 0; ni < 4; ni++)
                b[ni] = *(const bf16x8*)&Bs[(wn * 64 + ni * 16 + col) * 64 + ch8];
            #pragma unroll
            for (int mi = 0; mi < 4; mi++) {
                bf16x8 a = *(const bf16x8*)&As[(wm * 64 + mi * 16 + col) * 64 + ch8];
                #pragma unroll
                for (int ni = 0; ni < 4; ni++)
                    acc[mi][ni] = __builtin_amdgcn_mfma_f32_16x16x32_bf16(
                        a, b[ni], acc[mi][ni], 0, 0, 0);
            }
        }
    }

    __syncthreads();   // all LDS reads done before overlaying merge buffer
    // epilogue: per-wave top-2 of its 64 codes per z-row (keys: q<<13 | invid)
    unsigned (*ldsT)[4] = (unsigned (*)[4])(&As[0]);   // 2 KB overlay
    #pragma unroll
    for (int mi = 0; mi < 4; mi++) {
        #pragma unroll
        for (int r = 0; r < 4; r++) {
            unsigned k4[4];
            #pragma unroll
            for (int ni = 0; ni < 4; ni++) {
                unsigned q = (unsigned)acc[mi][ni][r];
                k4[ni] = (q << 13) | (invL - 16u * ni);
            }
            unsigned p1 = umaxu(k4[0], k4[1]), q1 = uminu(k4[0], k4[1]);
            unsigned p2 = umaxu(k4[2], k4[3]), q2 = uminu(k4[2], k4[3]);
            unsigned t1 = umaxu(p1, p2);
            unsigned t2 = umaxu(uminu(p1, p2), umaxu(q1, q2));
            unsigned m1 = t1;
            #pragma unroll
            for (int m = 8; m >= 1; m >>= 1)
                m1 = umaxu(m1, (unsigned)__shfl_xor((int)m1, m, 64));
            unsigned cc = (t1 == m1) ? t2 : t1;     // keys unique (code id bits)
            #pragma unroll
            for (int m = 8; m >= 1; m >>= 1)
                cc = umaxu(cc, (unsigned)__shfl_xor((int)cc, m, 64));
            if (col == 0) {
                int rowl = wm * 64 + mi * 16 + hi * 4 + r;
                ldsT[rowl][wn * 2]     = m1;
                ldsT[rowl][wn * 2 + 1] = cc;
            }
        }
    }
    __syncthreads();
    // merge wn pair -> per-128-code-tile top-2 (identical c1/c2 semantics)
    if (tid < 128) {
        int row = tid;
        unsigned a0 = ldsT[row][0], a1 = ldsT[row][1];
        unsigned b0 = ldsT[row][2], b1 = ldsT[row][3];
        unsigned t1 = umaxu(a0, b0);
        unsigned t2 = umaxu(uminu(a0, b0), umaxu(a1, b1));
        size_t o = (size_t)kt * N_PTS + z0 + row;
        c1[o] = t1;
        c2[o] = t2;
    }
}

// ---- 3. rescore: idx + loss only (no z read, no z_q write, no fast-path w) --
// loss identity: ||z - w||^2 = ||z||^2 - 2*score. Fast path uses the quantized
// key score ((q - 131072)/128, error <= 1/128 + bf16 noise -> ~3e-5 on final
// mean loss). Slow path tracks the winner's fp32 score.
__global__ __launch_bounds__(1024) void k_rescore(
        const float* __restrict__ z, const float* __restrict__ w,
        const unsigned* __restrict__ c1, const unsigned* __restrict__ c2,
        const float* __restrict__ zn2,
        float* __restrict__ out,
        unsigned* __restrict__ cnt, float* __restrict__ lossp) {
    __shared__ unsigned s1[64 * 17], s2[64 * 17];   // 8.5 KB
    const int t  = threadIdx.x;
    const int w0 = blockIdx.x * 16;
    {
        int kt = t >> 4, wo = t & 15;               // 64-B line per 16 threads
        s1[kt * 17 + wo] = c1[(size_t)kt * N_PTS + w0 + wo];
        s2[kt * 17 + wo] = c2[(size_t)kt * N_PTS + w0 + wo];
    }
    __syncthreads();
    const int wv   = t >> 6;       // 0..15 -> wid
    const int lane = t & 63;       // = kt
    const int wid  = w0 + wv;
    unsigned k1 = s1[lane * 17 + wv];
    unsigned k2 = s2[lane * 17 + wv];

    // global best m1 and runner-up m2 over all 128 keys (k1 >= k2 per lane)
    unsigned m1 = k1;
    #pragma unroll
    for (int m = 32; m >= 1; m >>= 1)
        m1 = umaxu(m1, (unsigned)__shfl_xor((int)m1, m, 64));
    unsigned e = (k1 == m1) ? k2 : k1;
    unsigned m2 = e;
    #pragma unroll
    for (int m = 32; m >= 1; m >>= 1)
        m2 = umaxu(m2, (unsigned)__shfl_xor((int)m2, m, 64));

    int idx = K_CODES - 1 - (int)(m1 & 0x1FFFu);
    float scf = ((float)(int)(m1 >> 13) - 131072.0f) * 0.0078125f;

    unsigned qthr = (m1 >> 13) - 96u;     // 0.75 fp32-score window
    if ((m2 >> 13) >= qthr) {             // wave-uniform slow path (~20%)
        unsigned long long best = 0ULL;
        float bsc = 0.f;
        #pragma unroll
        for (int j = 0; j < 2; j++) {
            unsigned cj = j ? k2 : k1;
            unsigned long long mask = __ballot((cj >> 13) >= qthr);
            while (mask) {
                int l = __ffsll((unsigned long long)mask) - 1;
                mask &= mask - 1;
                unsigned cwd = (unsigned)__shfl((int)cj, l, 64);
                int k = K_CODES - 1 - (int)(cwd & 0x1FFFu);
                float4 wr = *(const float4*)(w + (size_t)k * DIM + lane * 4);
                float s = 0.f, h = 0.f;
                {
                    const float* zr = z + (size_t)wid * DIM + lane * 4;
                    float4 zv = *(const float4*)zr;
                    s = zv.x * wr.x + zv.y * wr.y + zv.z * wr.z + zv.w * wr.w;
                    h = wr.x * wr.x + wr.y * wr.y + wr.z * wr.z + wr.w * wr.w;
                }
                #pragma unroll
                for (int m = 32; m >= 1; m >>= 1) {
                    s += __shfl_xor(s, m, 64);
                    h += __shfl_xor(h, m, 64);
                }
                float sc = s - 0.5f * h;
                unsigned u = __float_as_uint(sc);
                u = (u & 0x80000000u) ? ~u : (u | 0x80000000u);
                unsigned long long key = ((unsigned long long)u << 32)
                                       | (unsigned)(K_CODES - 1 - k);
                bool better = key > best;             // wave-uniform
                best = better ? key : best;
                bsc  = better ? sc  : bsc;
            }
        }
        idx = K_CODES - 1 - (int)(unsigned)(best & 0xFFFFFFFFull);
        scf = bsc;
    }

    if (lane == 0) {
        out[OFF_IDX + wid] = (float)idx;
        lossp[wid] = zn2[wid] - 2.0f * scf;
        atomicAdd(cnt + idx, 1u);
    }
}

// ---- 4. single-block: scan + new_cs + n + loss + fill (cursor in LDS) -------
__global__ __launch_bounds__(1024) void k_prefix(const float* __restrict__ csin,
                                                 float* __restrict__ out,
                                                 const unsigned* __restrict__ cnt,
                                                 unsigned* __restrict__ offs,
                                                 unsigned* __restrict__ list,
                                                 const float* __restrict__ lossp,
                                                 float* __restrict__ nval) {
    __shared__ unsigned scur[K_CODES];     // 32 KB LDS cursor
    __shared__ unsigned wtot[16], wbase[16];
    __shared__ float fred[16], fred2[16];
    int t = threadIdx.x, lane = t & 63, wv = t >> 6;
    int base = t * 8;
    unsigned c[8], mysum = 0;
    #pragma unroll
    for (int i = 0; i < 8; i++) { c[i] = cnt[base + i]; mysum += c[i]; }
    unsigned inc = mysum;
    #pragma unroll
    for (int off = 1; off < 64; off <<= 1) {
        unsigned v = (unsigned)__shfl_up((int)inc, off, 64);
        if (lane >= off) inc += v;
    }
    if (lane == 63) wtot[wv] = inc;
    __syncthreads();
    if (t == 0) {
        unsigned r = 0;
        for (int i = 0; i < 16; i++) { wbase[i] = r; r += wtot[i]; }
        offs[K_CODES] = r;
    }
    __syncthreads();
    unsigned my0 = wbase[wv] + inc - mysum;
    float csl = 0.f;
    #pragma unroll
    for (int i = 0; i < 8; i++) {
        offs[base + i] = my0;
        scur[base + i] = my0;
        my0 += c[i];
        float ncs = DECAYF * csin[base + i] + OMDF * (float)c[i];
        out[OFF_CS + base + i] = ncs;
        csl += ncs;
    }
    #pragma unroll
    for (int m = 32; m >= 1; m >>= 1) csl += __shfl_xor(csl, m, 64);
    if (lane == 0) fred[wv] = csl;
    float lp = 0.f;
    #pragma unroll
    for (int i = 0; i < 16; i++) lp += lossp[t + i * 1024];
    #pragma unroll
    for (int m = 32; m >= 1; m >>= 1) lp += __shfl_xor(lp, m, 64);
    if (lane == 0) fred2[wv] = lp;
    __syncthreads();
    if (t == 0) {
        float n = 0.f, L = 0.f;
        for (int i = 0; i < 16; i++) { n += fred[i]; L += fred2[i]; }
        *nval = n;
        out[OFF_LOSS] = L * (1.0f / ((float)N_PTS * DIM));
    }
    // fill phase: LDS-atomic cursors, scattered list writes
    for (int i = t; i < N_PTS; i += 1024) {
        int idx = (int)out[OFF_IDX + i];
        unsigned pos = atomicAdd(&scur[idx], 1u);
        list[pos] = (unsigned)i;
    }
}

// ---- 5. per-code gather: z_q scatter + new_ea + new_weight (no atomics) -----
__global__ void k_gather(const float* __restrict__ z, const float* __restrict__ ea,
                         const float* __restrict__ w,
                         float* __restrict__ out,
                         const unsigned* __restrict__ offs,
                         const unsigned* __restrict__ list,
                         const float* __restrict__ nval) {
    int k = blockIdx.x, lane = threadIdx.x;
    unsigned beg = offs[k], end = offs[k + 1];
    float4 wv = *(const float4*)(w + (size_t)k * DIM + lane * 4);
    float4 acc = {0.f, 0.f, 0.f, 0.f};
    for (unsigned p = beg; p < end; ++p) {
        unsigned i = list[p];
        float4 zv = *(const float4*)(z + (size_t)i * DIM + lane * 4);
        acc.x += zv.x; acc.y += zv.y; acc.z += zv.z; acc.w += zv.w;
        *(float4*)(out + OFF_ZQ + (size_t)i * DIM + lane * 4) = wv;  // z_q = w[idx]
    }
    float4 e = *(const float4*)(ea + (size_t)k * DIM + lane * 4);
    e.x = DECAYF * e.x + OMDF * acc.x;
    e.y = DECAYF * e.y + OMDF * acc.y;
    e.z = DECAYF * e.z + OMDF * acc.z;
    e.w = DECAYF * e.w + OMDF * acc.w;
    *(float4*)(out + OFF_EA + (size_t)k * DIM + lane * 4) = e;

    float cs = out[OFF_CS + k];
    float n  = *nval;
    float inv = 1.f / ((cs + EPSF) / (n + (float)K_CODES * EPSF) * n);
    float4 wr = {e.x * inv, e.y * inv, e.z * inv, e.w * inv};
    *(float4*)(out + OFF_W + (size_t)k * DIM + lane * 4) = wr;
}

extern "C" void kernel_launch(void* const* d_in, const int* in_sizes, int n_in,
                              void* d_out, int out_size, void* d_ws, size_t ws_size,
                              hipStream_t stream) {
    const float* z  = (const float*)d_in[0];
    const float* w  = (const float*)d_in[1];
    const float* cs = (const float*)d_in[2];
    const float* ea = (const float*)d_in[3];
    float* out = (float*)d_out;

    short*    zb  = (short*)(out + ZB_OFF);
    short*    wb  = (short*)(out + WB_OFF);
    float*    hen = out + HEN_OFF;
    unsigned* c1  = (unsigned*)(out + C1_OFF);
    unsigned* c2  = (unsigned*)(out + C2_OFF);

    // small scratch in d_ws (~262 KB)
    unsigned* cnt   = (unsigned*)d_ws;        // 8192
    unsigned* offs  = cnt + 8192;             // 8193 (padded to 8200)
    unsigned* list  = offs + 8200;            // 16384
    float*    lossp = (float*)(list + 16384); // 16384
    float*    nval  = lossp + 16384;          // 1
    float*    zn2   = nval + 1;               // 16384

    hipLaunchKernelGGL(k_cvt2,    dim3((N_PTS + K_CODES) * DIM / 2048), dim3(256), 0, stream,
                       z, zb, w, wb, hen, cnt, zn2);
    hipLaunchKernelGGL(k_gemm,    dim3((N_PTS / 128) * (K_CODES / 128)), dim3(256), 0, stream,
                       zb, wb, hen, c1, c2);
    hipLaunchKernelGGL(k_rescore, dim3(N_PTS / 16),           dim3(1024), 0, stream,
                       z, w, c1, c2, zn2, out, cnt, lossp);
    hipLaunchKernelGGL(k_prefix,  dim3(1),                    dim3(1024), 0, stream,
                       cs, out, cnt, offs, list, lossp, nval);
    hipLaunchKernelGGL(k_gather,  dim3(K_CODES),              dim3(64), 0, stream,
                       z, ea, w, out, offs, list, nval);
}

// Round 5
// 309.288 us; speedup vs baseline: 1.1958x; 1.1958x over previous
//
#include <hip/hip_runtime.h>
#include <cstdint>
#include <cstddef>

#define N_PTS   16384
#define K_CODES 8192
#define DIM     256
#define DECAYF  0.99f
#define OMDF    0.01f
#define EPSF    1e-5f

// output layout (float32, concatenated in reference return order)
#define OFF_ZQ   0
#define OFF_LOSS 4194304
#define OFF_IDX  4194305
#define OFF_W    4210689
#define OFF_CS   6307841
#define OFF_EA   6316033

// scratch parked inside output regions that are written later:
//  zb  = bf16[16384*256] at out+OFF_ZQ            (8 MB, = 128*z)  } z_q region,
//  wb  = bf16[ 8192*256] at out+OFF_ZQ+2097152    (4 MB)           } dead after
//  hen = f32 [ 8192]     at out+OFF_ZQ+3145728    (32 KB)          } k_gemm
//  c1,c2 = u32[64][16384] x2 at out+OFF_W         (8 MB exact fit; dead after
//                                                  k_rescore; k_gather rewrites)
#define ZB_OFF   OFF_ZQ
#define WB_OFF   (OFF_ZQ + 2097152)
#define HEN_OFF  (OFF_ZQ + 3145728)
#define C1_OFF   OFF_W
#define C2_OFF   (OFF_W + 1048576)

typedef __attribute__((ext_vector_type(8))) short bf16x8;
typedef __attribute__((ext_vector_type(4))) float f32x4;

__device__ inline unsigned short f2b(float f) {  // fp32 -> bf16 bits, RNE
    unsigned u = __float_as_uint(f);
    return (unsigned short)((u + 0x7FFFu + ((u >> 16) & 1u)) >> 16);
}

__device__ inline unsigned umaxu(unsigned a, unsigned b) { return a > b ? a : b; }
__device__ inline unsigned uminu(unsigned a, unsigned b) { return a < b ? a : b; }

__device__ inline void gload16(const void* g, void* l) {
    __builtin_amdgcn_global_load_lds(
        (const __attribute__((address_space(1))) unsigned int*)g,
        (__attribute__((address_space(3))) unsigned int*)l, 16, 0, 0);
}

// ---- 1. fp32 -> bf16 (z scaled by 128) + per-point ||z||^2 + hen + cnt zero -
__global__ void k_cvt2(const float* __restrict__ z, short* __restrict__ zb,
                       const float* __restrict__ w, short* __restrict__ wb,
                       float* __restrict__ hen, unsigned* __restrict__ cnt,
                       float* __restrict__ zn2) {
    const int tid = threadIdx.x;
    if (blockIdx.x < N_PTS * DIM / 2048) {
        size_t base = (size_t)(blockIdx.x * 256 + tid) * 8;
        float4 a = *(const float4*)(z + base);
        float4 b = *(const float4*)(z + base + 4);
        bf16x8 o;                                   // zb = 128*z (exact scale)
        o[0] = (short)f2b(128.f * a.x); o[1] = (short)f2b(128.f * a.y);
        o[2] = (short)f2b(128.f * a.z); o[3] = (short)f2b(128.f * a.w);
        o[4] = (short)f2b(128.f * b.x); o[5] = (short)f2b(128.f * b.y);
        o[6] = (short)f2b(128.f * b.z); o[7] = (short)f2b(128.f * b.w);
        *(bf16x8*)(zb + base) = o;
        // per-point ||z||^2 (32 threads per point)
        float s = a.x * a.x + a.y * a.y + a.z * a.z + a.w * a.w
                + b.x * b.x + b.y * b.y + b.z * b.z + b.w * b.w;
        #pragma unroll
        for (int m = 16; m >= 1; m >>= 1) s += __shfl_xor(s, m, 64);
        if ((tid & 31) == 0) zn2[blockIdx.x * 8 + (tid >> 5)] = s;
    } else {
        int blk = blockIdx.x - N_PTS * DIM / 2048;
        size_t base = (size_t)(blk * 256 + tid) * 8;
        float4 a = *(const float4*)(w + base);
        float4 b = *(const float4*)(w + base + 4);
        bf16x8 o;
        o[0] = (short)f2b(a.x); o[1] = (short)f2b(a.y);
        o[2] = (short)f2b(a.z); o[3] = (short)f2b(a.w);
        o[4] = (short)f2b(b.x); o[5] = (short)f2b(b.y);
        o[6] = (short)f2b(b.z); o[7] = (short)f2b(b.w);
        *(bf16x8*)(wb + base) = o;
        float s = a.x * a.x + a.y * a.y + a.z * a.z + a.w * a.w
                + b.x * b.x + b.y * b.y + b.z * b.z + b.w * b.w;
        #pragma unroll
        for (int m = 16; m >= 1; m >>= 1) s += __shfl_xor(s, m, 64);
        if ((tid & 31) == 0) hen[base >> 8] = 0.5f * s;
        int gid = blk * 256 + tid;
        if (gid < K_CODES) cnt[gid] = 0u;
    }
}

// ---- 2. bf16 MFMA GEMM, 64x128 tile, 4 waves (2Mx2N), 6 blocks/CU -----------
// Evidence R0-R3: MfmaUtil ~ 1.9% x waves/CU (latency/TLP-bound family).
// R4 lesson: launch_bounds(256,5) + acc[4][4]=64 AGPR forced spills (VGPR=48,
// WRITE_SIZE 188 MB scratch) -> never exceed the unified-file budget.
// This round: buy waves with LDS, pay with AGPRs:
//   wave tile 32x64 -> acc[2][4] = 32 AGPR; total regs ~80 <= 85 (6 waves/EU
//   budget) -> no spill. LDS 24 KB (A 8 + B 16) -> 6 blocks/CU = 24 waves/CU.
// Everything else verbatim from the proven rounds: 2-phase stage->sync->
// compute, same XOR swizzle / de-swizzle (0 bank conflicts measured), same K
// order (dc 0..3 x kk 0..1) -> bit-identical scores, same 64-code top-2 +
// wn-pair merge, same c1/c2 [64][16384] layout -> downstream untouched.
__global__ __launch_bounds__(256, 6) void k_gemm(const short* __restrict__ zb,
                                                 const short* __restrict__ wb,
                                                 const float* __restrict__ hen,
                                                 unsigned* __restrict__ c1,
                                                 unsigned* __restrict__ c2) {
    __shared__ __align__(16) short As[64 * 64];    //  8 KB (64 z-rows x 64 k)
    __shared__ __align__(16) short Bs[128 * 64];   // 16 KB (128 codes x 64 k)

    const int tid  = threadIdx.x;
    const int lane = tid & 63;
    const int wv   = tid >> 6;               // 0..3
    const int wm   = wv >> 1;                // 0..1  (z half: 32 rows)
    const int wn   = wv & 1;                 // 0..1  (code half: 64 cols)
    const int ztile = blockIdx.x & 255;      // kt-major: 256 blocks share B-tile
    const int kt    = blockIdx.x >> 8;       // 0..63
    const int z0 = ztile * 64, k0g = kt * 128;
    const int col = lane & 15;
    const int hi  = lane >> 4;
    const int x7  = lane & 7;

    f32x4 acc[2][4];
    #pragma unroll
    for (int ni = 0; ni < 4; ni++) {
        float h = 131072.0f - 128.0f * hen[k0g + wn * 64 + ni * 16 + col];
        f32x4 iv = {h, h, h, h};
        acc[0][ni] = iv; acc[1][ni] = iv;
    }
    const unsigned invL = (unsigned)(K_CODES - 1 - (k0g + wn * 64 + col));

    const int srow = lane >> 3;                       // 0..7 within segment
    const int scol = ((lane & 7) ^ srow) * 8;         // swizzled source chunk

    #pragma unroll 1
    for (int dc = 0; dc < 4; ++dc) {
        __syncthreads();
        // A: 8 segments of 8 rows (2 per wave); B: 16 segments (4 per wave)
        #pragma unroll
        for (int i = 0; i < 2; ++i) {
            int seg = wv * 2 + i;
            gload16(zb + (size_t)(z0 + seg * 8 + srow) * DIM + dc * 64 + scol,
                    As + seg * 512 + lane * 8);
        }
        #pragma unroll
        for (int i = 0; i < 4; ++i) {
            int seg = wv * 4 + i;
            gload16(wb + (size_t)(k0g + seg * 8 + srow) * DIM + dc * 64 + scol,
                    Bs + seg * 512 + lane * 8);
        }
        __syncthreads();
        #pragma unroll
        for (int kk = 0; kk < 2; ++kk) {
            const int ch8 = ((((kk << 2) + hi) ^ x7) << 3);   // de-swizzle
            bf16x8 b[4];
            #pragma unroll
            for (int ni = 0; ni < 4; ni++)
                b[ni] = *(const bf16x8*)&Bs[(wn * 64 + ni * 16 + col) * 64 + ch8];
            #pragma unroll
            for (int mi = 0; mi < 2; mi++) {
                bf16x8 a = *(const bf16x8*)&As[(wm * 32 + mi * 16 + col) * 64 + ch8];
                #pragma unroll
                for (int ni = 0; ni < 4; ni++)
                    acc[mi][ni] = __builtin_amdgcn_mfma_f32_16x16x32_bf16(
                        a, b[ni], acc[mi][ni], 0, 0, 0);
            }
        }
    }

    __syncthreads();   // all LDS reads done before overlaying merge buffer
    // epilogue: per-wave top-2 of its 64 codes per z-row (keys: q<<13 | invid)
    unsigned (*ldsT)[4] = (unsigned (*)[4])(&As[0]);   // 1 KB overlay
    #pragma unroll
    for (int mi = 0; mi < 2; mi++) {
        #pragma unroll
        for (int r = 0; r < 4; r++) {
            unsigned k4[4];
            #pragma unroll
            for (int ni = 0; ni < 4; ni++) {
                unsigned q = (unsigned)acc[mi][ni][r];
                k4[ni] = (q << 13) | (invL - 16u * ni);
            }
            unsigned p1 = umaxu(k4[0], k4[1]), q1 = uminu(k4[0], k4[1]);
            unsigned p2 = umaxu(k4[2], k4[3]), q2 = uminu(k4[2], k4[3]);
            unsigned t1 = umaxu(p1, p2);
            unsigned t2 = umaxu(uminu(p1, p2), umaxu(q1, q2));
            unsigned m1 = t1;
            #pragma unroll
            for (int m = 8; m >= 1; m >>= 1)
                m1 = umaxu(m1, (unsigned)__shfl_xor((int)m1, m, 64));
            unsigned cc = (t1 == m1) ? t2 : t1;     // keys unique (code id bits)
            #pragma unroll
            for (int m = 8; m >= 1; m >>= 1)
                cc = umaxu(cc, (unsigned)__shfl_xor((int)cc, m, 64));
            if (col == 0) {
                int rowl = wm * 32 + mi * 16 + hi * 4 + r;
                ldsT[rowl][wn * 2]     = m1;
                ldsT[rowl][wn * 2 + 1] = cc;
            }
        }
    }
    __syncthreads();
    // merge wn pair -> per-128-code-tile top-2 (identical c1/c2 semantics)
    if (tid < 64) {
        int row = tid;
        unsigned a0 = ldsT[row][0], a1 = ldsT[row][1];
        unsigned b0 = ldsT[row][2], b1 = ldsT[row][3];
        unsigned t1 = umaxu(a0, b0);
        unsigned t2 = umaxu(uminu(a0, b0), umaxu(a1, b1));
        size_t o = (size_t)kt * N_PTS + z0 + row;
        c1[o] = t1;
        c2[o] = t2;
    }
}

// ---- 3. rescore: idx + loss only (no z read, no z_q write, no fast-path w) --
// loss identity: ||z - w||^2 = ||z||^2 - 2*score. Fast path uses the quantized
// key score ((q - 131072)/128, error <= 1/128 + bf16 noise -> ~3e-5 on final
// mean loss). Slow path tracks the winner's fp32 score.
__global__ __launch_bounds__(1024) void k_rescore(
        const float* __restrict__ z, const float* __restrict__ w,
        const unsigned* __restrict__ c1, const unsigned* __restrict__ c2,
        const float* __restrict__ zn2,
        float* __restrict__ out,
        unsigned* __restrict__ cnt, float* __restrict__ lossp) {
    __shared__ unsigned s1[64 * 17], s2[64 * 17];   // 8.5 KB
    const int t  = threadIdx.x;
    const int w0 = blockIdx.x * 16;
    {
        int kt = t >> 4, wo = t & 15;               // 64-B line per 16 threads
        s1[kt * 17 + wo] = c1[(size_t)kt * N_PTS + w0 + wo];
        s2[kt * 17 + wo] = c2[(size_t)kt * N_PTS + w0 + wo];
    }
    __syncthreads();
    const int wv   = t >> 6;       // 0..15 -> wid
    const int lane = t & 63;       // = kt
    const int wid  = w0 + wv;
    unsigned k1 = s1[lane * 17 + wv];
    unsigned k2 = s2[lane * 17 + wv];

    // global best m1 and runner-up m2 over all 128 keys (k1 >= k2 per lane)
    unsigned m1 = k1;
    #pragma unroll
    for (int m = 32; m >= 1; m >>= 1)
        m1 = umaxu(m1, (unsigned)__shfl_xor((int)m1, m, 64));
    unsigned e = (k1 == m1) ? k2 : k1;
    unsigned m2 = e;
    #pragma unroll
    for (int m = 32; m >= 1; m >>= 1)
        m2 = umaxu(m2, (unsigned)__shfl_xor((int)m2, m, 64));

    int idx = K_CODES - 1 - (int)(m1 & 0x1FFFu);
    float scf = ((float)(int)(m1 >> 13) - 131072.0f) * 0.0078125f;

    unsigned qthr = (m1 >> 13) - 96u;     // 0.75 fp32-score window
    if ((m2 >> 13) >= qthr) {             // wave-uniform slow path (~20%)
        unsigned long long best = 0ULL;
        float bsc = 0.f;
        #pragma unroll
        for (int j = 0; j < 2; j++) {
            unsigned cj = j ? k2 : k1;
            unsigned long long mask = __ballot((cj >> 13) >= qthr);
            while (mask) {
                int l = __ffsll((unsigned long long)mask) - 1;
                mask &= mask - 1;
                unsigned cwd = (unsigned)__shfl((int)cj, l, 64);
                int k = K_CODES - 1 - (int)(cwd & 0x1FFFu);
                float4 wr = *(const float4*)(w + (size_t)k * DIM + lane * 4);
                float s = 0.f, h = 0.f;
                {
                    const float* zr = z + (size_t)wid * DIM + lane * 4;
                    float4 zv = *(const float4*)zr;
                    s = zv.x * wr.x + zv.y * wr.y + zv.z * wr.z + zv.w * wr.w;
                    h = wr.x * wr.x + wr.y * wr.y + wr.z * wr.z + wr.w * wr.w;
                }
                #pragma unroll
                for (int m = 32; m >= 1; m >>= 1) {
                    s += __shfl_xor(s, m, 64);
                    h += __shfl_xor(h, m, 64);
                }
                float sc = s - 0.5f * h;
                unsigned u = __float_as_uint(sc);
                u = (u & 0x80000000u) ? ~u : (u | 0x80000000u);
                unsigned long long key = ((unsigned long long)u << 32)
                                       | (unsigned)(K_CODES - 1 - k);
                bool better = key > best;             // wave-uniform
                best = better ? key : best;
                bsc  = better ? sc  : bsc;
            }
        }
        idx = K_CODES - 1 - (int)(unsigned)(best & 0xFFFFFFFFull);
        scf = bsc;
    }

    if (lane == 0) {
        out[OFF_IDX + wid] = (float)idx;
        lossp[wid] = zn2[wid] - 2.0f * scf;
        atomicAdd(cnt + idx, 1u);
    }
}

// ---- 4. single-block: scan + new_cs + n + loss + fill (cursor in LDS) -------
__global__ __launch_bounds__(1024) void k_prefix(const float* __restrict__ csin,
                                                 float* __restrict__ out,
                                                 const unsigned* __restrict__ cnt,
                                                 unsigned* __restrict__ offs,
                                                 unsigned* __restrict__ list,
                                                 const float* __restrict__ lossp,
                                                 float* __restrict__ nval) {
    __shared__ unsigned scur[K_CODES];     // 32 KB LDS cursor
    __shared__ unsigned wtot[16], wbase[16];
    __shared__ float fred[16], fred2[16];
    int t = threadIdx.x, lane = t & 63, wv = t >> 6;
    int base = t * 8;
    unsigned c[8], mysum = 0;
    #pragma unroll
    for (int i = 0; i < 8; i++) { c[i] = cnt[base + i]; mysum += c[i]; }
    unsigned inc = mysum;
    #pragma unroll
    for (int off = 1; off < 64; off <<= 1) {
        unsigned v = (unsigned)__shfl_up((int)inc, off, 64);
        if (lane >= off) inc += v;
    }
    if (lane == 63) wtot[wv] = inc;
    __syncthreads();
    if (t == 0) {
        unsigned r = 0;
        for (int i = 0; i < 16; i++) { wbase[i] = r; r += wtot[i]; }
        offs[K_CODES] = r;
    }
    __syncthreads();
    unsigned my0 = wbase[wv] + inc - mysum;
    float csl = 0.f;
    #pragma unroll
    for (int i = 0; i < 8; i++) {
        offs[base + i] = my0;
        scur[base + i] = my0;
        my0 += c[i];
        float ncs = DECAYF * csin[base + i] + OMDF * (float)c[i];
        out[OFF_CS + base + i] = ncs;
        csl += ncs;
    }
    #pragma unroll
    for (int m = 32; m >= 1; m >>= 1) csl += __shfl_xor(csl, m, 64);
    if (lane == 0) fred[wv] = csl;
    float lp = 0.f;
    #pragma unroll
    for (int i = 0; i < 16; i++) lp += lossp[t + i * 1024];
    #pragma unroll
    for (int m = 32; m >= 1; m >>= 1) lp += __shfl_xor(lp, m, 64);
    if (lane == 0) fred2[wv] = lp;
    __syncthreads();
    if (t == 0) {
        float n = 0.f, L = 0.f;
        for (int i = 0; i < 16; i++) { n += fred[i]; L += fred2[i]; }
        *nval = n;
        out[OFF_LOSS] = L * (1.0f / ((float)N_PTS * DIM));
    }
    // fill phase: LDS-atomic cursors, scattered list writes
    for (int i = t; i < N_PTS; i += 1024) {
        int idx = (int)out[OFF_IDX + i];
        unsigned pos = atomicAdd(&scur[idx], 1u);
        list[pos] = (unsigned)i;
    }
}

// ---- 5. per-code gather: z_q scatter + new_ea + new_weight (no atomics) -----
__global__ void k_gather(const float* __restrict__ z, const float* __restrict__ ea,
                         const float* __restrict__ w,
                         float* __restrict__ out,
                         const unsigned* __restrict__ offs,
                         const unsigned* __restrict__ list,
                         const float* __restrict__ nval) {
    int k = blockIdx.x, lane = threadIdx.x;
    unsigned beg = offs[k], end = offs[k + 1];
    float4 wv = *(const float4*)(w + (size_t)k * DIM + lane * 4);
    float4 acc = {0.f, 0.f, 0.f, 0.f};
    for (unsigned p = beg; p < end; ++p) {
        unsigned i = list[p];
        float4 zv = *(const float4*)(z + (size_t)i * DIM + lane * 4);
        acc.x += zv.x; acc.y += zv.y; acc.z += zv.z; acc.w += zv.w;
        *(float4*)(out + OFF_ZQ + (size_t)i * DIM + lane * 4) = wv;  // z_q = w[idx]
    }
    float4 e = *(const float4*)(ea + (size_t)k * DIM + lane * 4);
    e.x = DECAYF * e.x + OMDF * acc.x;
    e.y = DECAYF * e.y + OMDF * acc.y;
    e.z = DECAYF * e.z + OMDF * acc.z;
    e.w = DECAYF * e.w + OMDF * acc.w;
    *(float4*)(out + OFF_EA + (size_t)k * DIM + lane * 4) = e;

    float cs = out[OFF_CS + k];
    float n  = *nval;
    float inv = 1.f / ((cs + EPSF) / (n + (float)K_CODES * EPSF) * n);
    float4 wr = {e.x * inv, e.y * inv, e.z * inv, e.w * inv};
    *(float4*)(out + OFF_W + (size_t)k * DIM + lane * 4) = wr;
}

extern "C" void kernel_launch(void* const* d_in, const int* in_sizes, int n_in,
                              void* d_out, int out_size, void* d_ws, size_t ws_size,
                              hipStream_t stream) {
    const float* z  = (const float*)d_in[0];
    const float* w  = (const float*)d_in[1];
    const float* cs = (const float*)d_in[2];
    const float* ea = (const float*)d_in[3];
    float* out = (float*)d_out;

    short*    zb  = (short*)(out + ZB_OFF);
    short*    wb  = (short*)(out + WB_OFF);
    float*    hen = out + HEN_OFF;
    unsigned* c1  = (unsigned*)(out + C1_OFF);
    unsigned* c2  = (unsigned*)(out + C2_OFF);

    // small scratch in d_ws (~262 KB)
    unsigned* cnt   = (unsigned*)d_ws;        // 8192
    unsigned* offs  = cnt + 8192;             // 8193 (padded to 8200)
    unsigned* list  = offs + 8200;            // 16384
    float*    lossp = (float*)(list + 16384); // 16384
    float*    nval  = lossp + 16384;          // 1
    float*    zn2   = nval + 1;               // 16384

    hipLaunchKernelGGL(k_cvt2,    dim3((N_PTS + K_CODES) * DIM / 2048), dim3(256), 0, stream,
                       z, zb, w, wb, hen, cnt, zn2);
    hipLaunchKernelGGL(k_gemm,    dim3((N_PTS / 64) * (K_CODES / 128)), dim3(256), 0, stream,
                       zb, wb, hen, c1, c2);
    hipLaunchKernelGGL(k_rescore, dim3(N_PTS / 16),           dim3(1024), 0, stream,
                       z, w, c1, c2, zn2, out, cnt, lossp);
    hipLaunchKernelGGL(k_prefix,  dim3(1),                    dim3(1024), 0, stream,
                       cs, out, cnt, offs, list, lossp, nval);
    hipLaunchKernelGGL(k_gather,  dim3(K_CODES),              dim3(64), 0, stream,
                       z, ea, w, out, offs, list, nval);
}

// Round 6
// 237.764 us; speedup vs baseline: 1.5555x; 1.3008x over previous
//
#include <hip/hip_runtime.h>
#include <cstdint>
#include <cstddef>

#define N_PTS   16384
#define K_CODES 8192
#define DIM     256
#define DECAYF  0.99f
#define OMDF    0.01f
#define EPSF    1e-5f

// output layout (float32, concatenated in reference return order)
#define OFF_ZQ   0
#define OFF_LOSS 4194304
#define OFF_IDX  4194305
#define OFF_W    4210689
#define OFF_CS   6307841
#define OFF_EA   6316033

// scratch parked inside output regions that are written later:
//  zb  = bf16[16384*256] at out+OFF_ZQ            (8 MB, = 128*z)  } z_q region,
//  wb  = bf16[ 8192*256] at out+OFF_ZQ+2097152    (4 MB)           } dead after
//  hen = f32 [ 8192]     at out+OFF_ZQ+3145728    (32 KB)          } k_gemm
//  c1,c2 = u32[64][16384] x2 at out+OFF_W         (8 MB exact fit; dead after
//                                                  k_rescore; k_gather rewrites)
#define ZB_OFF   OFF_ZQ
#define WB_OFF   (OFF_ZQ + 2097152)
#define HEN_OFF  (OFF_ZQ + 3145728)
#define C1_OFF   OFF_W
#define C2_OFF   (OFF_W + 1048576)

typedef __attribute__((ext_vector_type(8))) short bf16x8;
typedef __attribute__((ext_vector_type(4))) float f32x4;

__device__ inline unsigned short f2b(float f) {  // fp32 -> bf16 bits, RNE
    unsigned u = __float_as_uint(f);
    return (unsigned short)((u + 0x7FFFu + ((u >> 16) & 1u)) >> 16);
}

__device__ inline unsigned umaxu(unsigned a, unsigned b) { return a > b ? a : b; }
__device__ inline unsigned uminu(unsigned a, unsigned b) { return a < b ? a : b; }

__device__ inline void gload16(const void* g, void* l) {
    __builtin_amdgcn_global_load_lds(
        (const __attribute__((address_space(1))) unsigned int*)g,
        (__attribute__((address_space(3))) unsigned int*)l, 16, 0, 0);
}

// ---- 1. fp32 -> bf16 (z scaled by 128) + per-point ||z||^2 + hen + cnt zero -
__global__ void k_cvt2(const float* __restrict__ z, short* __restrict__ zb,
                       const float* __restrict__ w, short* __restrict__ wb,
                       float* __restrict__ hen, unsigned* __restrict__ cnt,
                       float* __restrict__ zn2) {
    const int tid = threadIdx.x;
    if (blockIdx.x < N_PTS * DIM / 2048) {
        size_t base = (size_t)(blockIdx.x * 256 + tid) * 8;
        float4 a = *(const float4*)(z + base);
        float4 b = *(const float4*)(z + base + 4);
        bf16x8 o;                                   // zb = 128*z (exact scale)
        o[0] = (short)f2b(128.f * a.x); o[1] = (short)f2b(128.f * a.y);
        o[2] = (short)f2b(128.f * a.z); o[3] = (short)f2b(128.f * a.w);
        o[4] = (short)f2b(128.f * b.x); o[5] = (short)f2b(128.f * b.y);
        o[6] = (short)f2b(128.f * b.z); o[7] = (short)f2b(128.f * b.w);
        *(bf16x8*)(zb + base) = o;
        // per-point ||z||^2 (32 threads per point)
        float s = a.x * a.x + a.y * a.y + a.z * a.z + a.w * a.w
                + b.x * b.x + b.y * b.y + b.z * b.z + b.w * b.w;
        #pragma unroll
        for (int m = 16; m >= 1; m >>= 1) s += __shfl_xor(s, m, 64);
        if ((tid & 31) == 0) zn2[blockIdx.x * 8 + (tid >> 5)] = s;
    } else {
        int blk = blockIdx.x - N_PTS * DIM / 2048;
        size_t base = (size_t)(blk * 256 + tid) * 8;
        float4 a = *(const float4*)(w + base);
        float4 b = *(const float4*)(w + base + 4);
        bf16x8 o;
        o[0] = (short)f2b(a.x); o[1] = (short)f2b(a.y);
        o[2] = (short)f2b(a.z); o[3] = (short)f2b(a.w);
        o[4] = (short)f2b(b.x); o[5] = (short)f2b(b.y);
        o[6] = (short)f2b(b.z); o[7] = (short)f2b(b.w);
        *(bf16x8*)(wb + base) = o;
        float s = a.x * a.x + a.y * a.y + a.z * a.z + a.w * a.w
                + b.x * b.x + b.y * b.y + b.z * b.z + b.w * b.w;
        #pragma unroll
        for (int m = 16; m >= 1; m >>= 1) s += __shfl_xor(s, m, 64);
        if ((tid & 31) == 0) hen[base >> 8] = 0.5f * s;
        int gid = blk * 256 + tid;
        if (gid < K_CODES) cnt[gid] = 0u;
    }
}

// ---- 2. bf16 MFMA GEMM + top-2 candidates per (z, 128-code tile) ------------
// EXACT round-0 kernel (measured 97-99 us, best of 6 structural variants).
// 128z x 128k tile, 4 waves stacked in z (32z x 128k), acc 2x8 = 64 AGPRs,
// single live B-fragment set, __launch_bounds__(256,4) -> 4 blocks/CU,
// kt-major coalesced c1/c2 writes. R1-R5 post-mortems: every geometry/schedule
// deviation (256^2 2ph/8ph, 256x128, 128^2@5blk(spill), 64x128@6blk) lost;
// this point is Pareto-optimal in the family. Do not touch without A/B.
__global__ __launch_bounds__(256, 4) void k_gemm(const short* __restrict__ zb,
                                                 const short* __restrict__ wb,
                                                 const float* __restrict__ hen,
                                                 unsigned* __restrict__ c1,
                                                 unsigned* __restrict__ c2) {
    __shared__ __align__(16) short As[128 * 64];   // 16 KB
    __shared__ __align__(16) short Bs[128 * 64];   // 16 KB

    const int tid  = threadIdx.x;
    const int lane = tid & 63;
    const int wv   = tid >> 6;
    const int ztile = blockIdx.x & 127;      // kt-major: 128 blocks share B-tile
    const int kt    = blockIdx.x >> 7;       // 0..63
    const int z0 = ztile * 128, k0 = kt * 128;
    const int col = lane & 15;

    f32x4 acc[2][8];
    #pragma unroll
    for (int ni = 0; ni < 8; ni++) {
        float h = 131072.0f - 128.0f * hen[k0 + ni * 16 + col];
        f32x4 iv = {h, h, h, h};
        acc[0][ni] = iv; acc[1][ni] = iv;
    }
    const unsigned inv0 = (unsigned)(K_CODES - 1 - (k0 + col));

    const int srow = lane >> 3;                       // 0..7 within segment
    const int scol = ((lane & 7) ^ srow) * 8;         // swizzled source chunk

    #pragma unroll
    for (int dc = 0; dc < 4; ++dc) {
        __syncthreads();
        #pragma unroll
        for (int s4 = 0; s4 < 4; ++s4) {
            int seg = wv * 4 + s4;                    // 16 segments of 8 rows
            gload16(zb + (size_t)(z0 + seg * 8 + srow) * DIM + dc * 64 + scol,
                    As + seg * 512 + lane * 8);
            gload16(wb + (size_t)(k0 + seg * 8 + srow) * DIM + dc * 64 + scol,
                    Bs + seg * 512 + lane * 8);
        }
        __syncthreads();
        #pragma unroll
        for (int kk = 0; kk < 2; ++kk) {
            int ch = ((kk << 2) + (lane >> 4)) ^ (lane & 7);   // de-swizzle
            bf16x8 a0 = *(const bf16x8*)&As[(wv * 32 + col) * 64 + ch * 8];
            bf16x8 a1 = *(const bf16x8*)&As[(wv * 32 + 16 + col) * 64 + ch * 8];
            #pragma unroll
            for (int ni = 0; ni < 8; ni++) {
                bf16x8 b = *(const bf16x8*)&Bs[(ni * 16 + col) * 64 + ch * 8];
                acc[0][ni] = __builtin_amdgcn_mfma_f32_16x16x32_bf16(
                    a0, b, acc[0][ni], 0, 0, 0);
                acc[1][ni] = __builtin_amdgcn_mfma_f32_16x16x32_bf16(
                    a1, b, acc[1][ni], 0, 0, 0);
            }
        }
    }

    // epilogue: per z-row top-2 of 128 codes, coalesced kt-major writes
    #pragma unroll
    for (int mi = 0; mi < 2; mi++) {
        #pragma unroll
        for (int r = 0; r < 4; r++) {
            unsigned k8[8];
            #pragma unroll
            for (int ni = 0; ni < 8; ni++) {
                unsigned q = (unsigned)acc[mi][ni][r];         // v_cvt_u32_f32
                k8[ni] = (q << 13) | (inv0 - 16u * ni);        // v_lshl_or_b32
            }
            unsigned p1 = umaxu(k8[0], k8[1]), q1 = uminu(k8[0], k8[1]);
            unsigned p2 = umaxu(k8[2], k8[3]), q2 = uminu(k8[2], k8[3]);
            unsigned p3 = umaxu(k8[4], k8[5]), q3 = uminu(k8[4], k8[5]);
            unsigned p4 = umaxu(k8[6], k8[7]), q4 = uminu(k8[6], k8[7]);
            unsigned a1 = umaxu(p1, p2);
            unsigned a2 = umaxu(uminu(p1, p2), umaxu(q1, q2));
            unsigned b1 = umaxu(p3, p4);
            unsigned b2 = umaxu(uminu(p3, p4), umaxu(q3, q4));
            unsigned t1 = umaxu(a1, b1);
            unsigned t2 = umaxu(uminu(a1, b1), umaxu(a2, b2));
            unsigned m1 = t1;
            #pragma unroll
            for (int m = 8; m >= 1; m >>= 1)
                m1 = umaxu(m1, (unsigned)__shfl_xor((int)m1, m, 64));
            unsigned cc = (t1 == m1) ? t2 : t1;     // keys unique (code id bits)
            #pragma unroll
            for (int m = 8; m >= 1; m >>= 1)
                cc = umaxu(cc, (unsigned)__shfl_xor((int)cc, m, 64));
            if (col == 0) {
                int row = wv * 32 + mi * 16 + (lane >> 4) * 4 + r;
                c1[(size_t)kt * N_PTS + z0 + row] = m1;
                c2[(size_t)kt * N_PTS + z0 + row] = cc;
            }
        }
    }
}

// ---- 3. rescore: idx + loss only (no z read, no z_q write, no fast-path w) --
// loss identity: ||z - w||^2 = ||z||^2 - 2*score. Fast path uses the quantized
// key score ((q - 131072)/128, error <= 1/128 + bf16 noise -> ~3e-5 on final
// mean loss). Slow path tracks the winner's fp32 score.
__global__ __launch_bounds__(1024) void k_rescore(
        const float* __restrict__ z, const float* __restrict__ w,
        const unsigned* __restrict__ c1, const unsigned* __restrict__ c2,
        const float* __restrict__ zn2,
        float* __restrict__ out,
        unsigned* __restrict__ cnt, float* __restrict__ lossp) {
    __shared__ unsigned s1[64 * 17], s2[64 * 17];   // 8.5 KB
    const int t  = threadIdx.x;
    const int w0 = blockIdx.x * 16;
    {
        int kt = t >> 4, wo = t & 15;               // 64-B line per 16 threads
        s1[kt * 17 + wo] = c1[(size_t)kt * N_PTS + w0 + wo];
        s2[kt * 17 + wo] = c2[(size_t)kt * N_PTS + w0 + wo];
    }
    __syncthreads();
    const int wv   = t >> 6;       // 0..15 -> wid
    const int lane = t & 63;       // = kt
    const int wid  = w0 + wv;
    unsigned k1 = s1[lane * 17 + wv];
    unsigned k2 = s2[lane * 17 + wv];

    // global best m1 and runner-up m2 over all 128 keys (k1 >= k2 per lane)
    unsigned m1 = k1;
    #pragma unroll
    for (int m = 32; m >= 1; m >>= 1)
        m1 = umaxu(m1, (unsigned)__shfl_xor((int)m1, m, 64));
    unsigned e = (k1 == m1) ? k2 : k1;
    unsigned m2 = e;
    #pragma unroll
    for (int m = 32; m >= 1; m >>= 1)
        m2 = umaxu(m2, (unsigned)__shfl_xor((int)m2, m, 64));

    int idx = K_CODES - 1 - (int)(m1 & 0x1FFFu);
    float scf = ((float)(int)(m1 >> 13) - 131072.0f) * 0.0078125f;

    unsigned qthr = (m1 >> 13) - 96u;     // 0.75 fp32-score window
    if ((m2 >> 13) >= qthr) {             // wave-uniform slow path (~20%)
        unsigned long long best = 0ULL;
        float bsc = 0.f;
        #pragma unroll
        for (int j = 0; j < 2; j++) {
            unsigned cj = j ? k2 : k1;
            unsigned long long mask = __ballot((cj >> 13) >= qthr);
            while (mask) {
                int l = __ffsll((unsigned long long)mask) - 1;
                mask &= mask - 1;
                unsigned cwd = (unsigned)__shfl((int)cj, l, 64);
                int k = K_CODES - 1 - (int)(cwd & 0x1FFFu);
                float4 wr = *(const float4*)(w + (size_t)k * DIM + lane * 4);
                float s = 0.f, h = 0.f;
                {
                    const float* zr = z + (size_t)wid * DIM + lane * 4;
                    float4 zv = *(const float4*)zr;
                    s = zv.x * wr.x + zv.y * wr.y + zv.z * wr.z + zv.w * wr.w;
                    h = wr.x * wr.x + wr.y * wr.y + wr.z * wr.z + wr.w * wr.w;
                }
                #pragma unroll
                for (int m = 32; m >= 1; m >>= 1) {
                    s += __shfl_xor(s, m, 64);
                    h += __shfl_xor(h, m, 64);
                }
                float sc = s - 0.5f * h;
                unsigned u = __float_as_uint(sc);
                u = (u & 0x80000000u) ? ~u : (u | 0x80000000u);
                unsigned long long key = ((unsigned long long)u << 32)
                                       | (unsigned)(K_CODES - 1 - k);
                bool better = key > best;             // wave-uniform
                best = better ? key : best;
                bsc  = better ? sc  : bsc;
            }
        }
        idx = K_CODES - 1 - (int)(unsigned)(best & 0xFFFFFFFFull);
        scf = bsc;
    }

    if (lane == 0) {
        out[OFF_IDX + wid] = (float)idx;
        lossp[wid] = zn2[wid] - 2.0f * scf;
        atomicAdd(cnt + idx, 1u);
    }
}

// ---- 4. single-block: scan + new_cs + n + loss + fill (cursor in LDS) -------
// fill phase: 16 indices loaded up-front (independent loads, one latency)
// then 16 LDS-atomic + scatter; previously 16 dependent load->atomic rounds.
__global__ __launch_bounds__(1024) void k_prefix(const float* __restrict__ csin,
                                                 float* __restrict__ out,
                                                 const unsigned* __restrict__ cnt,
                                                 unsigned* __restrict__ offs,
                                                 unsigned* __restrict__ list,
                                                 const float* __restrict__ lossp,
                                                 float* __restrict__ nval) {
    __shared__ unsigned scur[K_CODES];     // 32 KB LDS cursor
    __shared__ unsigned wtot[16], wbase[16];
    __shared__ float fred[16], fred2[16];
    int t = threadIdx.x, lane = t & 63, wv = t >> 6;
    int base = t * 8;
    unsigned c[8], mysum = 0;
    #pragma unroll
    for (int i = 0; i < 8; i++) { c[i] = cnt[base + i]; mysum += c[i]; }
    unsigned inc = mysum;
    #pragma unroll
    for (int off = 1; off < 64; off <<= 1) {
        unsigned v = (unsigned)__shfl_up((int)inc, off, 64);
        if (lane >= off) inc += v;
    }
    if (lane == 63) wtot[wv] = inc;
    __syncthreads();
    if (t == 0) {
        unsigned r = 0;
        for (int i = 0; i < 16; i++) { wbase[i] = r; r += wtot[i]; }
        offs[K_CODES] = r;
    }
    __syncthreads();
    unsigned my0 = wbase[wv] + inc - mysum;
    float csl = 0.f;
    #pragma unroll
    for (int i = 0; i < 8; i++) {
        offs[base + i] = my0;
        scur[base + i] = my0;
        my0 += c[i];
        float ncs = DECAYF * csin[base + i] + OMDF * (float)c[i];
        out[OFF_CS + base + i] = ncs;
        csl += ncs;
    }
    #pragma unroll
    for (int m = 32; m >= 1; m >>= 1) csl += __shfl_xor(csl, m, 64);
    if (lane == 0) fred[wv] = csl;
    float lp = 0.f;
    #pragma unroll
    for (int i = 0; i < 16; i++) lp += lossp[t + i * 1024];
    #pragma unroll
    for (int m = 32; m >= 1; m >>= 1) lp += __shfl_xor(lp, m, 64);
    if (lane == 0) fred2[wv] = lp;
    __syncthreads();
    if (t == 0) {
        float n = 0.f, L = 0.f;
        for (int i = 0; i < 16; i++) { n += fred[i]; L += fred2[i]; }
        *nval = n;
        out[OFF_LOSS] = L * (1.0f / ((float)N_PTS * DIM));
    }
    // fill phase: batched loads, then LDS-atomic cursors + scattered writes
    {
        int idxs[16];
        #pragma unroll
        for (int j = 0; j < 16; j++)
            idxs[j] = (int)out[OFF_IDX + t + j * 1024];
        #pragma unroll
        for (int j = 0; j < 16; j++) {
            unsigned pos = atomicAdd(&scur[idxs[j]], 1u);
            list[pos] = (unsigned)(t + j * 1024);
        }
    }
}

// ---- 5. per-code gather: z_q scatter + new_ea + new_weight (no atomics) -----
// 4 waves per code stride the point list (skew-tolerant: max serial chain is
// ceil(cnt/4) instead of cnt); partial sums reduced through LDS; wave 0 does
// the ea/weight epilogue. fp32 reorder noise ~1e-6 pre-EMA (tolerated).
__global__ __launch_bounds__(256) void k_gather(
        const float* __restrict__ z, const float* __restrict__ ea,
        const float* __restrict__ w,
        float* __restrict__ out,
        const unsigned* __restrict__ offs,
        const unsigned* __restrict__ list,
        const float* __restrict__ nval) {
    __shared__ float sacc[3][256];          // 3 KB partials from waves 1..3
    const int k    = blockIdx.x;
    const int lane = threadIdx.x & 63;
    const int wvi  = threadIdx.x >> 6;      // 0..3
    const unsigned beg = offs[k], end = offs[k + 1];
    float4 wr4 = *(const float4*)(w + (size_t)k * DIM + lane * 4);
    float ax = 0.f, ay = 0.f, az = 0.f, aw = 0.f;
    for (unsigned p = beg + wvi; p < end; p += 4) {
        unsigned i = list[p];
        float4 zv = *(const float4*)(z + (size_t)i * DIM + lane * 4);
        ax += zv.x; ay += zv.y; az += zv.z; aw += zv.w;
        *(float4*)(out + OFF_ZQ + (size_t)i * DIM + lane * 4) = wr4;  // z_q
    }
    if (wvi > 0) {
        float4 t4 = {ax, ay, az, aw};
        *(float4*)&sacc[wvi - 1][lane * 4] = t4;
    }
    __syncthreads();
    if (wvi == 0) {
        #pragma unroll
        for (int j = 0; j < 3; j++) {
            float4 t4 = *(const float4*)&sacc[j][lane * 4];
            ax += t4.x; ay += t4.y; az += t4.z; aw += t4.w;
        }
        float4 e = *(const float4*)(ea + (size_t)k * DIM + lane * 4);
        e.x = DECAYF * e.x + OMDF * ax;
        e.y = DECAYF * e.y + OMDF * ay;
        e.z = DECAYF * e.z + OMDF * az;
        e.w = DECAYF * e.w + OMDF * aw;
        *(float4*)(out + OFF_EA + (size_t)k * DIM + lane * 4) = e;

        float cs = out[OFF_CS + k];
        float n  = *nval;
        float inv = 1.f / ((cs + EPSF) / (n + (float)K_CODES * EPSF) * n);
        float4 wr = {e.x * inv, e.y * inv, e.z * inv, e.w * inv};
        *(float4*)(out + OFF_W + (size_t)k * DIM + lane * 4) = wr;
    }
}

extern "C" void kernel_launch(void* const* d_in, const int* in_sizes, int n_in,
                              void* d_out, int out_size, void* d_ws, size_t ws_size,
                              hipStream_t stream) {
    const float* z  = (const float*)d_in[0];
    const float* w  = (const float*)d_in[1];
    const float* cs = (const float*)d_in[2];
    const float* ea = (const float*)d_in[3];
    float* out = (float*)d_out;

    short*    zb  = (short*)(out + ZB_OFF);
    short*    wb  = (short*)(out + WB_OFF);
    float*    hen = out + HEN_OFF;
    unsigned* c1  = (unsigned*)(out + C1_OFF);
    unsigned* c2  = (unsigned*)(out + C2_OFF);

    // small scratch in d_ws (~262 KB)
    unsigned* cnt   = (unsigned*)d_ws;        // 8192
    unsigned* offs  = cnt + 8192;             // 8193 (padded to 8200)
    unsigned* list  = offs + 8200;            // 16384
    float*    lossp = (float*)(list + 16384); // 16384
    float*    nval  = lossp + 16384;          // 1
    float*    zn2   = nval + 1;               // 16384

    hipLaunchKernelGGL(k_cvt2,    dim3((N_PTS + K_CODES) * DIM / 2048), dim3(256), 0, stream,
                       z, zb, w, wb, hen, cnt, zn2);
    hipLaunchKernelGGL(k_gemm,    dim3((N_PTS / 128) * (K_CODES / 128)), dim3(256), 0, stream,
                       zb, wb, hen, c1, c2);
    hipLaunchKernelGGL(k_rescore, dim3(N_PTS / 16),           dim3(1024), 0, stream,
                       z, w, c1, c2, zn2, out, cnt, lossp);
    hipLaunchKernelGGL(k_prefix,  dim3(1),                    dim3(1024), 0, stream,
                       cs, out, cnt, offs, list, lossp, nval);
    hipLaunchKernelGGL(k_gather,  dim3(K_CODES),              dim3(256), 0, stream,
                       z, ea, w, out, offs, list, nval);
}